// Round 6
// baseline (263.202 us; speedup 1.0000x reference)
//
#include <hip/hip_runtime.h>
#include <math.h>

#define WIN 11
#define PAD 5
#define TW 64              // tile width = wave width

typedef float v2f __attribute__((ext_vector_type(2)));

struct GW { float g[WIN]; };

// ---------------------------------------------------------------------------
// Wave-autonomous SSIM tile, SOFTWARE-PIPELINED edition.
// R0-R5 invariant: row service ~1040 cyc/wave, VALU only ~435, insensitive to
// everything tried -> waves stall in LOCKSTEP on the per-row serial chain
// ds_write -> ds_read x11 -> ~120cy -> H-conv -> V-conv.
// Fix: pipeline one row ahead so every latency is covered by a full row body:
//   iter t: [issue ds_reads row t+1 (dbuf)] -> [V-conv(t)+emit with h(t) regs,
//   overlapping read latency] -> [H-conv(t+1) -> h regs] -> [write row t+2
//   from depth-2 prefetch into other LDS buffer; pool there (EMIT)].
// Dependence spans: reads(t+1)->H(t+1) covered by V-conv(t); write(t+2)->
// reads(t+2) covered by one iteration; loads(t+4)->write(t+2 regs) two.
// Double-buffer parity (t&1) is ADDRESS math only (no runtime reg indexing).
// Retained: static V-ring (u-unroll 11, zero shift movs), scalar float[11]
// accumulators w/ static indices (R1 spill trap), branchless loads (R5),
// sched_barrier(0) row pinning (R8 unroll-hoist spill trap).
// Tripwire: WRITE_SIZE must stay ~24.8MB; growth = scratch spill = revert.
// EMIT: L0 waves also pool rows pairwise into L1 (a=(P+Q)/2, b=(P-Q)/2),
// done at the WRITE phase (row r=t+2), same row set as R4/R5.
// ---------------------------------------------------------------------------
template<bool EMIT>
__device__ __forceinline__ float ssim_wave_tile(
    const float* __restrict__ p1, const float* __restrict__ p2,
    int W, int X0, int Y0, const GW& gw, float2* __restrict__ rb,
    float* __restrict__ o1a, float* __restrict__ o1b, int Wout)
{
    const int TH = 32;
    const int lane = threadIdx.x & 63;
    const int gx = X0 + lane;
    const bool cval = gx < W;                              // false only for L4 lanes 32+
    const int hx   = (lane < 5) ? (X0 - 5 + lane) : (X0 + 59 + lane);
    const bool hval = (lane < 10) && ((unsigned)hx < (unsigned)W);
    const int hpos = (lane < 5) ? lane : (64 + lane);      // 0..4 | 69..73
    const int cpos = 5 + lane;
    const int gxc = cval ? gx : 0;                         // clamped main col
    const int hxc = hval ? hx : gxc;                       // masked halo -> own col (L1 hit)
    const int wpos = (lane < 10) ? hpos : cpos;            // branchless LDS halo write

    float vMp[11], vSp[11], vMq[11], vSq[11];
#pragma unroll
    for (int k = 0; k < 11; ++k) { vMp[k] = 0.f; vSp[k] = 0.f; vMq[k] = 0.f; vSq[k] = 0.f; }

    float part = 0.f;
    float pprev = 0.f, qprev = 0.f;

    // BRANCHLESS load: 4 unconditional global_load_dword per row, results
    // zero-selected. Statically uniform load count -> counted vmcnt.
    auto LOAD = [&](int t, float& oa, float& ob, float& oah, float& obh) {
        int y = Y0 - PAD + t;
        bool yin = (unsigned)y < (unsigned)W;
        const float* r1 = p1 + (size_t)(yin ? y : 0) * W;
        const float* r2 = p2 + (size_t)(yin ? y : 0) * W;
        float va = r1[gxc], vb = r2[gxc];
        float wa = r1[hxc], wb = r2[hxc];
        bool cv = yin && cval;
        bool hv = yin && hval;
        oa  = cv ? va : 0.f;
        ob  = cv ? vb : 0.f;
        oah = hv ? wa : 0.f;
        obh = hv ? wb : 0.f;
    };

    // ---------------- prologue: establish pipeline invariant for t=0 -------
    // invariant at top of iter t: h = H(t); LDS buf[(t+1)&1] holds row t+1;
    // (a0..) = raw row t+2; (a1..) = raw row t+3 (in flight).
    float a0, b0, ah0, bh0;    // row t+2
    float a1, b1, ah1, bh1;    // row t+3
    float hp, hq, hpp, hqq;    // H-conv of row t
    {
        float t0a, t0b, t0ah, t0bh;
        float t1a, t1b, t1ah, t1bh;
        LOAD(0, t0a, t0b, t0ah, t0bh);
        LOAD(1, t1a, t1b, t1ah, t1bh);
        LOAD(2, a0, b0, ah0, bh0);

        // write row 0 -> buf0
        float p = t0a + t0b, q = t0a - t0b;
        float ph = t0ah + t0bh, qh = t0ah - t0bh;
        rb[cpos] = make_float2(p, q);
        rb[wpos] = (lane < 10) ? make_float2(ph, qh) : make_float2(p, q);
        __builtin_amdgcn_wave_barrier();

        LOAD(3, a1, b1, ah1, bh1);

        // H(0) from buf0
        v2f hM = {0.f, 0.f}, hS = {0.f, 0.f};
#pragma unroll
        for (int j = 0; j < WIN; ++j) {
            float2 v = rb[lane + j];
            v2f vm = { v.x, v.y };
            v2f g2 = { gw.g[j], gw.g[j] };
            hM = __builtin_elementwise_fma(g2, vm, hM);
            hS = __builtin_elementwise_fma(g2, vm * vm, hS);
        }
        __builtin_amdgcn_wave_barrier();
        hp = hM.x; hq = hM.y; hpp = hS.x; hqq = hS.y;

        // write row 1 -> buf1
        float p1_ = t1a + t1b, q1_ = t1a - t1b;
        float ph1 = t1ah + t1bh, qh1 = t1ah - t1bh;
        rb[80 + cpos] = make_float2(p1_, q1_);
        rb[80 + wpos] = (lane < 10) ? make_float2(ph1, qh1) : make_float2(p1_, q1_);
        __builtin_amdgcn_wave_barrier();
        pprev = p1_; qprev = q1_;
    }

    // ---------------- main pipelined loop: 44 iterations (4 x 11) ----------
#pragma unroll 1
    for (int blk = 0; blk < 4; ++blk) {
#pragma unroll
        for (int u = 0; u < 11; ++u) {
            const int t = blk * 11 + u;          // u compile-time, blk runtime
            const int rOff = (((blk & 1) ^ (u & 1)) ^ 1) * 80;  // buf of row t+1
            const int wOff = ((blk & 1) ^ (u & 1)) * 80;        // buf for row t+2

            // 1) issue reads of row t+1 (latency covered by V-conv below)
            float2 v[11];
#pragma unroll
            for (int j = 0; j < WIN; ++j) v[j] = rb[rOff + lane + j];

            // 2) issue prefetch of row t+4 (consumed 2 iterations from now)
            float a2, b2, ah2, bh2;
            LOAD(t + 4, a2, b2, ah2, bh2);

            // 3) V-conv(t) static ring with h(t) regs — pure VALU, no LDS dep
#pragma unroll
            for (int s = 0; s < 11; ++s) {
                const int widx = 10 - ((s - u + 11) % 11);
                float g = gw.g[widx];
                vMp[s] = fmaf(g, hp,  vMp[s]);
                vSp[s] = fmaf(g, hpp, vSp[s]);
                vMq[s] = fmaf(g, hq,  vMq[s]);
                vSq[s] = fmaf(g, hqq, vSq[s]);
            }

            // slot u completes output o = t-10 this row (after its g[10] tap)
            {
                int o = t - 10;
                if ((unsigned)o < (unsigned)TH) {
                    bool yok = (unsigned)(Y0 + o) < (unsigned)W;   // false only for L4 tail
                    float Mp = vMp[u], Sp_ = vSp[u], Mq = vMq[u], Sq_ = vSq[u];
                    const float C1v = 1e-4f, C2v = 9e-4f;
                    float A = Mp * Mp, B = Mq * Mq;
                    float ABp = A + B, ABm = A - B;
                    float SSp = Sp_ + Sq_, SSm = Sp_ - Sq_;
                    float n1 = fmaf(0.5f, ABm, C1v);         // 2*m12 + C1
                    float n2 = fmaf(0.5f, SSm - ABm, C2v);   // 2*s12 + C2
                    float e1 = fmaf(0.5f, ABp, C1v);         // m1^2+m2^2 + C1
                    float e2 = fmaf(0.5f, SSp - ABp, C2v);   // s1+s2 + C2
                    float val = (n1 * n2) * __builtin_amdgcn_rcpf(e1 * e2);
                    part += (cval && yok) ? val : 0.f;
                }
                vMp[u] = 0.f; vSp[u] = 0.f; vMq[u] = 0.f; vSq[u] = 0.f;
            }

            // 4) H-conv(t+1) from the reads issued in (1)
            {
                v2f hM = {0.f, 0.f}, hS = {0.f, 0.f};
#pragma unroll
                for (int j = 0; j < WIN; ++j) {
                    v2f vm = { v[j].x, v[j].y };
                    v2f g2 = { gw.g[j], gw.g[j] };
                    hM = __builtin_elementwise_fma(g2, vm, hM);
                    hS = __builtin_elementwise_fma(g2, vm * vm, hS);
                }
                hp = hM.x; hq = hM.y; hpp = hS.x; hqq = hS.y;
            }

            // 5) write row t+2 into the other buffer; pool there (EMIT)
            {
                float p = a0 + b0, q = a0 - b0;
                float ph = ah0 + bh0, qh = ah0 - bh0;
                rb[wOff + cpos] = make_float2(p, q);
                rb[wOff + wpos] = (lane < 10) ? make_float2(ph, qh) : make_float2(p, q);
                __builtin_amdgcn_wave_barrier();

                if (EMIT) {
                    int r = t + 2;
                    if (r >= 6 && r <= TH + 4 && (r & 1) == 0) {   // pool rows (r-1, r)
                        float sp_ = p + pprev, sq_ = q + qprev;
                        float sp2 = sp_ + __shfl_down(sp_, 1, 64);
                        float sq2 = sq_ + __shfl_down(sq_, 1, 64);
                        if ((lane & 1) == 0) {
                            float P = sp2 * 0.25f, Q = sq2 * 0.25f;
                            int yo = (r - 6) >> 1;
                            size_t oo = (size_t)((Y0 >> 1) + yo) * Wout + ((X0 >> 1) + (lane >> 1));
                            o1a[oo] = (P + Q) * 0.5f;
                            o1b[oo] = (P - Q) * 0.5f;
                        }
                    }
                    pprev = p; qprev = q;
                }
            }

            // rotate prefetch pipeline
            a0 = a1; b0 = b1; ah0 = ah1; bh0 = bh1;
            a1 = a2; b1 = b2; ah1 = ah2; bh1 = bh2;

            // pin row boundary: no load hoisting / cross-row motion (R8 trap)
            __builtin_amdgcn_sched_barrier(0);
        }
    }

    return part;
}

// ---- L0: 8x16 tiles (64x32) x 48 images = 6144 waves (1536 blocks); emits L1 ----
__global__ __launch_bounds__(256, 4) void ssim_l0_kernel(
    const float* __restrict__ i1, const float* __restrict__ i2,
    float* __restrict__ a1, float* __restrict__ b1,
    double* __restrict__ acc, GW gw)
{
    __shared__ float2 rbs[4][160];          // double-buffered 80-slot rows
    const int wid = threadIdx.x >> 6;
    const int w = blockIdx.x * 4 + wid;
    const int img = w >> 7;                 // 128 tiles per image
    const int tt = w & 127;
    const int tx = tt & 7, ty = tt >> 3;    // 8 cols x 16 rows
    const size_t off  = (size_t)img * 512 * 512;
    const size_t ooff = (size_t)img * 256 * 256;

    float part = ssim_wave_tile<true>(i1 + off, i2 + off, 512, tx * 64, ty * 32,
                                      gw, rbs[wid], a1 + ooff, b1 + ooff, 256);
#pragma unroll
    for (int o = 32; o > 0; o >>= 1) part += __shfl_down(part, o, 64);
    if ((threadIdx.x & 63) == 0) atomicAdd(acc, (double)part);
}

// ---- L1..L4, all 64x32 tiles: 32+8+2+1 = 43 tiles/image = 2064 waves (516 blocks) ----
__global__ __launch_bounds__(256, 4) void ssim_rest_kernel(
    const float* __restrict__ a1, const float* __restrict__ b1,
    const float* __restrict__ a2, const float* __restrict__ b2,
    const float* __restrict__ a3, const float* __restrict__ b3,
    const float* __restrict__ a4, const float* __restrict__ b4,
    double* __restrict__ acc, GW gw)
{
    __shared__ float2 rbs[4][160];
    const int wid = threadIdx.x >> 6;
    const int w = blockIdx.x * 4 + wid;
    const int img = w / 43;
    const int r = w - img * 43;
    int lvl, tx, ty;
    if (r < 32)      { lvl = 1; tx = r & 3;  ty = r >> 2; }                // 4x8
    else if (r < 40) { lvl = 2; int s = r - 32; tx = s & 1; ty = s >> 1; } // 2x4
    else if (r < 42) { lvl = 3; tx = 0; ty = r - 40; }                     // 1x2
    else             { lvl = 4; tx = 0; ty = 0; }                          // 1x1
    const int W = 512 >> lvl;
    const float* p1; const float* p2;
    switch (lvl) {
      case 1:  p1 = a1; p2 = b1; break;
      case 2:  p1 = a2; p2 = b2; break;
      case 3:  p1 = a3; p2 = b3; break;
      default: p1 = a4; p2 = b4; break;
    }
    const size_t off = (size_t)img * W * W;

    float part = ssim_wave_tile<false>(p1 + off, p2 + off, W, tx * 64, ty * 32,
                                       gw, rbs[wid], nullptr, nullptr, 0);
#pragma unroll
    for (int o = 32; o > 0; o >>= 1) part += __shfl_down(part, o, 64);
    if ((threadIdx.x & 63) == 0) atomicAdd(acc + lvl, (double)part);
}

// ---- pool L1 -> L2/L3/L4. Grid (16, 96). ----
__global__ __launch_bounds__(256) void pool_rest_kernel(
    const float* __restrict__ a1, const float* __restrict__ b1,
    float* __restrict__ a2, float* __restrict__ b2,
    float* __restrict__ a3, float* __restrict__ b3,
    float* __restrict__ a4, float* __restrict__ b4)
{
    __shared__ float l2[32][33];
    __shared__ float l3[16][17];
    const int tid = threadIdx.x;
    const int im = blockIdx.y;
    const int tb = blockIdx.x;
    const int tx = tb & 3, ty = tb >> 2;
    const bool second = im >= 48;
    const int ii = second ? im - 48 : im;
    const float* src = (second ? b1 : a1) + (size_t)ii * 256 * 256;
    float* o2 = (second ? b2 : a2) + (size_t)ii * 128 * 128;
    float* o3 = (second ? b3 : a3) + (size_t)ii * 64 * 64;
    float* o4 = (second ? b4 : a4) + (size_t)ii * 32 * 32;
    const int X0 = tx * 64, Y0 = ty * 64;

#pragma unroll
    for (int k = 0; k < 2; ++k) {
        int idx = tid + k * 256;
        int xp = idx & 15;
        int yo = idx >> 4;
        const float* rp = src + (size_t)(Y0 + 2 * yo) * 256 + (X0 + 4 * xp);
        float4 r0 = *(const float4*)rp;
        float4 r1 = *(const float4*)(rp + 256);
        float v0 = (r0.x + r0.y + r1.x + r1.y) * 0.25f;
        float v1 = (r0.z + r0.w + r1.z + r1.w) * 0.25f;
        l2[yo][2 * xp]     = v0;
        l2[yo][2 * xp + 1] = v1;
        float2* op = (float2*)(o2 + (size_t)((Y0 >> 1) + yo) * 128 + ((X0 >> 1) + 2 * xp));
        *op = make_float2(v0, v1);
    }
    __syncthreads();
    {
        int xo = tid & 15, yo = tid >> 4;
        if (yo < 16) {
            float v = (l2[2*yo][2*xo] + l2[2*yo][2*xo+1] +
                       l2[2*yo+1][2*xo] + l2[2*yo+1][2*xo+1]) * 0.25f;
            l3[yo][xo] = v;
            o3[(size_t)((Y0 >> 2) + yo) * 64 + ((X0 >> 2) + xo)] = v;
        }
    }
    __syncthreads();
    if (tid < 64) {
        int xo = tid & 7, yo = tid >> 3;
        float v = (l3[2*yo][2*xo] + l3[2*yo][2*xo+1] +
                   l3[2*yo+1][2*xo] + l3[2*yo+1][2*xo+1]) * 0.25f;
        o4[(size_t)((Y0 >> 3) + yo) * 32 + ((X0 >> 3) + xo)] = v;
    }
}

__global__ void final_kernel(const double* __restrict__ acc, float* __restrict__ out)
{
    double loss = 0.0;
#pragma unroll
    for (int l = 0; l < 5; ++l) {
        double cnt = 48.0 * (double)(512 >> l) * (double)(512 >> l);
        loss += 1.0 - acc[l] / cnt;
    }
    out[0] = (float)loss;
}

extern "C" void kernel_launch(void* const* d_in, const int* in_sizes, int n_in,
                              void* d_out, int out_size, void* d_ws, size_t ws_size,
                              hipStream_t stream)
{
    const float* img1 = (const float*)d_in[0];
    const float* img2 = (const float*)d_in[1];
    float* out = (float*)d_out;

    // 1D gaussian (sigma=1.5, k=11), matches reference construction
    GW gw;
    double gs[WIN], sum = 0.0;
    for (int i = 0; i < WIN; ++i) {
        double ax = (double)i - 5.0;
        gs[i] = exp(-(ax * ax) / 4.5);
        sum += gs[i];
    }
    for (int i = 0; i < WIN; ++i) gw.g[i] = (float)(gs[i] / sum);

    // workspace: 64B header (5 double acc), then pyramid
    double* acc = (double*)d_ws;
    float* base = (float*)((char*)d_ws + 64);
    const size_t n1 = 48ull * 256 * 256;
    const size_t n2 = 48ull * 128 * 128;
    const size_t n3 = 48ull * 64 * 64;
    const size_t n4 = 48ull * 32 * 32;
    float* a1 = base;      float* b1 = a1 + n1;
    float* a2 = b1 + n1;   float* b2 = a2 + n2;
    float* a3 = b2 + n2;   float* b3 = a3 + n3;
    float* a4 = b3 + n3;   float* b4 = a4 + n4;

    hipMemsetAsync(acc, 0, 5 * sizeof(double), stream);

    hipLaunchKernelGGL(ssim_l0_kernel, dim3(1536), dim3(256), 0, stream,
                       img1, img2, a1, b1, acc, gw);

    hipLaunchKernelGGL(pool_rest_kernel, dim3(16, 96), dim3(256), 0, stream,
                       a1, b1, a2, b2, a3, b3, a4, b4);

    hipLaunchKernelGGL(ssim_rest_kernel, dim3(516), dim3(256), 0, stream,
                       a1, b1, a2, b2, a3, b3, a4, b4, acc, gw);

    hipLaunchKernelGGL(final_kernel, dim3(1), dim3(1), 0, stream, acc, out);
}